// Round 6
// baseline (500.108 us; speedup 1.0000x reference)
//
#include <hip/hip_runtime.h>

#define T_IN   512
#define T_OUT  128
#define BATCH  65536

typedef float v2f __attribute__((ext_vector_type(2)));

__device__ __forceinline__ float rcp_fast(float v) { return __builtin_amdgcn_rcpf(v); }

// Packed fp32 ops (VOP3P), forced via asm. In-place variant avoids reg copies.
__device__ __forceinline__ v2f pk_fma(v2f a, v2f b, v2f c) {
    v2f d;
    asm("v_pk_fma_f32 %0, %1, %2, %3" : "=v"(d) : "v"(a), "v"(b), "v"(c));
    return d;
}
__device__ __forceinline__ void pk_fma_ip(v2f& acc, v2f a, v2f b) {
    asm("v_pk_fma_f32 %0, %1, %2, %0" : "+v"(acc) : "v"(a), "v"(b));
}
__device__ __forceinline__ v2f pk_mul(v2f a, v2f b) {
    v2f d;
    asm("v_pk_mul_f32 %0, %1, %2" : "=v"(d) : "v"(a), "v"(b));
    return d;
}
__device__ __forceinline__ v2f pk_add(v2f a, v2f b) {
    v2f d;
    asm("v_pk_add_f32 %0, %1, %2" : "=v"(d) : "v"(a), "v"(b));
    return d;
}

// DPP cross-lane mov (VALU pipe, no LDS).
template<int CTRL>
__device__ __forceinline__ float dppf(float v) {
    return __int_as_float(__builtin_amdgcn_mov_dpp(__float_as_int(v), CTRL, 0xF, 0xF, false));
}
#define QP_XOR1 0xB1       // quad_perm [1,0,3,2]  : lane ^= 1
#define QP_XOR2 0x4E       // quad_perm [2,3,0,1]  : lane ^= 2
#define QP_XOR3 0x1B       // quad_perm [3,2,1,0]  : lane ^= 3
#define HALF_MIRROR 0x141  // row_half_mirror      : lane ^= 7 (within 8-lane halves)

struct ND { v2f num, den; };

// 8 lanes per unit-group; each thread carries TWO slot-packed batch elements.
// Activations via Pade[7/6] rational tanh on the packed pipe (NO exp2):
//   tanh(x) = x(135135+17325x^2+378x^4+x^6)/(135135+62370x^2+3150x^4+28x^6)
//   sigmoid(s) = 0.5 + 0.5*tanh(s/2)  -> 0.5 pre-folded into r,z weights.
// Per cell2 only 3 v_rcp_f32 (pairwise-merged per gate) touch the trans unit.
__global__ __launch_bounds__(256, 4) void gru_seq2seq(
    const float* __restrict__ x,
    const float* __restrict__ eWih, const float* __restrict__ eWhh,
    const float* __restrict__ eBih, const float* __restrict__ eBhh,
    const float* __restrict__ dWih, const float* __restrict__ dWhh,
    const float* __restrict__ dBih, const float* __restrict__ dBhh,
    const float* __restrict__ fcW,  const float* __restrict__ fcB,
    float* __restrict__ out)
{
    const int tid = threadIdx.x;
    const int u   = tid & 7;                        // owned hidden unit
    const int e0  = (int)blockIdx.x * 64 + (tid >> 3);   // slot0; slot1 = e0+32

    auto dup = [](float v) { return v2f{v, v}; };

    // Pade coefficients (dup'd into reg pairs; VOP3P takes no literals)
    const v2f cA0 = dup(135135.f), cA1 = dup(17325.f), cA2 = dup(378.f);
    const v2f cB1 = dup(62370.f),  cB2 = dup(3150.f),  cB3 = dup(28.f);
    const v2f cM1 = dup(-1.f), cHALF = dup(0.5f);

    v2f wr[8], wz[8], wn[8];                        // W_hh, XOR-ordered, dup'd
    v2f wirv, wizv, winv;                           // W_ih rows, dup'd
    v2f brv, bzv, bnv, binv;                        // bias seeds, dup'd

    auto load_w = [&](const float* Wih, const float* Whh,
                      const float* Bih, const float* Bhh) {
        #pragma unroll
        for (int d = 0; d < 8; ++d) {
            const int c = u ^ d;
            wr[d] = dup(Whh[u*8      + c] * 0.5f);  // sigmoid arg /2
            wz[d] = dup(Whh[(u+8)*8  + c] * 0.5f);
            wn[d] = dup(Whh[(u+16)*8 + c] * 0.5f);  // hn_half = 0.5*h_n
        }
        wirv = dup(Wih[u]    * 0.5f);
        wizv = dup(Wih[u+8]  * 0.5f);
        winv = dup(Wih[u+16]);                      // i_n at true scale
        brv  = dup((Bih[u]   + Bhh[u])   * 0.5f);
        bzv  = dup((Bih[u+8] + Bhh[u+8]) * 0.5f);
        bnv  = dup(Bhh[u+16] * 0.5f);
        binv = dup(Bih[u+16]);
    };

    load_w(eWih, eWhh, eBih, eBhh);

    v2f hp[8];                                      // hp[d] = {h0[u^d], h1[u^d]}
    #pragma unroll
    for (int d = 0; d < 8; ++d) hp[d] = v2f{0.f, 0.f};

    // Pade numerator/denominator, all packed ops
    auto poly_nd = [&](v2f y) -> ND {
        v2f t  = pk_mul(y, y);
        v2f nu = pk_add(t, cA2);
        nu = pk_fma(nu, t, cA1);
        nu = pk_fma(nu, t, cA0);
        nu = pk_mul(nu, y);
        v2f de = pk_fma(cB3, t, cB2);
        de = pk_fma(de, t, cB1);
        de = pk_fma(de, t, cA0);
        return ND{nu, de};
    };
    // merged reciprocal for one gate (2 slots share 1 v_rcp_f32)
    auto finishT = [&](ND nd) -> v2f {
        const float pr = rcp_fast(nd.den.x * nd.den.y);
        return v2f{ nd.num.x * (nd.den.y * pr), nd.num.y * (nd.den.x * pr) };
    };

    auto cell2 = [&](v2f xp) {
        // three gate matmuls (bias-seeded via out-of-place first fma)
        v2f ar = pk_fma(wr[0], hp[0], brv);
        v2f az = pk_fma(wz[0], hp[0], bzv);
        v2f an = pk_fma(wn[0], hp[0], bnv);
        #pragma unroll
        for (int d = 1; d < 8; ++d) {
            pk_fma_ip(ar, wr[d], hp[d]);
            pk_fma_ip(az, wz[d], hp[d]);
            pk_fma_ip(an, wn[d], hp[d]);
        }
        const v2f sr = pk_fma(xp, wirv, ar);        // y_r = s_r/2
        const v2f sz = pk_fma(xp, wizv, az);        // y_z = s_z/2
        const v2f p0 = pk_fma(xp, winv, binv);      // i_n (true scale)

        const v2f Tr = finishT(poly_nd(sr));        // tanh(s_r/2)
        const v2f Tz = finishT(poly_nd(sz));        // tanh(s_z/2)

        // pre = i_n + r*h_n = p0 + an + Tr*an   (an = 0.5*h_n)
        v2f pre = pk_fma(Tr, an, pk_add(p0, an));
        pre.x = fminf(fmaxf(pre.x, -5.5f), 5.5f);   // VOP2 literals, Pade-safe range
        pre.y = fminf(fmaxf(pre.y, -5.5f), 5.5f);
        const v2f n01 = finishT(poly_nd(pre));      // n = tanh(pre)

        // h' = (1-z)n + zh = 0.5*((h+n) + Tz*(h-n))
        const v2f hpn = pk_add(hp[0], n01);
        const v2f hmn = pk_fma(n01, cM1, hp[0]);
        const v2f q   = pk_fma(Tz, hmn, hpn);
        hp[0] = pk_mul(q, cHALF);

        // allgather (14 DPP): d=1,2,3,7 from h; d=6,5,4 from d=7
        const float g0 = hp[0].x, g1 = hp[0].y;
        const float a7x = dppf<HALF_MIRROR>(g0);
        const float a7y = dppf<HALF_MIRROR>(g1);
        hp[1] = v2f{ dppf<QP_XOR1>(g0), dppf<QP_XOR1>(g1) };
        hp[2] = v2f{ dppf<QP_XOR2>(g0), dppf<QP_XOR2>(g1) };
        hp[3] = v2f{ dppf<QP_XOR3>(g0), dppf<QP_XOR3>(g1) };
        hp[7] = v2f{ a7x, a7y };
        hp[6] = v2f{ dppf<QP_XOR1>(a7x), dppf<QP_XOR1>(a7y) };
        hp[5] = v2f{ dppf<QP_XOR2>(a7x), dppf<QP_XOR2>(a7y) };
        hp[4] = v2f{ dppf<QP_XOR3>(a7x), dppf<QP_XOR3>(a7y) };
    };

    // ---------------- encoder: 512 steps, prefetch distance 2, tail peeled ----------------
    const float* xp = x + e0;
    v2f xa0 = { xp[0],     xp[32] };
    v2f xa1 = { xp[BATCH], xp[BATCH + 32] };
    xp += 2 * (size_t)BATCH;
    #pragma unroll 2
    for (int t = 0; t < T_IN - 2; ++t) {
        const v2f xa2 = { xp[0], xp[32] };
        xp += BATCH;
        cell2(xa0);
        xa0 = xa1; xa1 = xa2;
    }
    cell2(xa0);      // t = 510
    cell2(xa1);      // t = 511; xa1 == x[511] == decoder first input

    // ---------------- decoder: 128 steps ----------------
    load_w(dWih, dWhh, dBih, dBhh);
    v2f fw[8];
    #pragma unroll
    for (int d = 0; d < 8; ++d) fw[d] = dup(fcW[u ^ d]);
    const v2f fbv = dup(fcB[0]);

    v2f inp = xa1;
    float* outp = out + e0;
    #pragma unroll 1
    for (int t = 0; t < T_OUT; ++t) {
        cell2(inp);
        v2f ay = pk_fma(fw[0], hp[0], fbv);
        #pragma unroll
        for (int d = 1; d < 8; ++d) pk_fma_ip(ay, fw[d], hp[d]);
        if (u == 0) {
            outp[t * BATCH]      = ay.x;
            outp[t * BATCH + 32] = ay.y;
        }
        inp = ay;
    }
}

extern "C" void kernel_launch(void* const* d_in, const int* in_sizes, int n_in,
                              void* d_out, int out_size, void* d_ws, size_t ws_size,
                              hipStream_t stream) {
    const float* x    = (const float*)d_in[0];
    const float* eWih = (const float*)d_in[1];
    const float* eWhh = (const float*)d_in[2];
    const float* eBih = (const float*)d_in[3];
    const float* eBhh = (const float*)d_in[4];
    const float* dWih = (const float*)d_in[5];
    const float* dWhh = (const float*)d_in[6];
    const float* dBih = (const float*)d_in[7];
    const float* dBhh = (const float*)d_in[8];
    const float* fcW  = (const float*)d_in[9];
    const float* fcB  = (const float*)d_in[10];
    float* out = (float*)d_out;

    dim3 grid(BATCH / 64);   // 1024 blocks; 2 elements per thread
    dim3 block(256);
    gru_seq2seq<<<grid, block, 0, stream>>>(x, eWih, eWhh, eBih, eBhh,
                                            dWih, dWhh, dBih, dBhh,
                                            fcW, fcB, out);
}

// Round 7
// 345.213 us; speedup vs baseline: 1.4487x; 1.4487x over previous
//
#include <hip/hip_runtime.h>

#define T_IN   512
#define T_OUT  128
#define BATCH  65536

typedef float v2f __attribute__((ext_vector_type(2)));

__device__ __forceinline__ float rcp_fast(float v) { return __builtin_amdgcn_rcpf(v); }
__device__ __forceinline__ float exp2_fast(float v) { return __builtin_amdgcn_exp2f(v); }

// ---- VOP3P packed fp32 ops, forced via asm ----
__device__ __forceinline__ v2f pk_fma(v2f a, v2f b, v2f c) {
    v2f d;
    asm("v_pk_fma_f32 %0, %1, %2, %3" : "=v"(d) : "v"(a), "v"(b), "v"(c));
    return d;
}
__device__ __forceinline__ void pk_fma_ip(v2f& acc, v2f a, v2f b) {
    asm("v_pk_fma_f32 %0, %1, %2, %0" : "+v"(acc) : "v"(a), "v"(b));
}
__device__ __forceinline__ v2f pk_mul(v2f a, v2f b) {
    v2f d;
    asm("v_pk_mul_f32 %0, %1, %2" : "=v"(d) : "v"(a), "v"(b));
    return d;
}
__device__ __forceinline__ v2f pk_add(v2f a, v2f b) {
    v2f d;
    asm("v_pk_add_f32 %0, %1, %2" : "=v"(d) : "v"(a), "v"(b));
    return d;
}
// acc += w * {h.lo, h.lo}   (src1 broadcast-lo via op_sel)
__device__ __forceinline__ void pk_fma_L(v2f& acc, v2f w, v2f h) {
    asm("v_pk_fma_f32 %0, %1, %2, %0 op_sel:[0,0,0] op_sel_hi:[1,0,1]"
        : "+v"(acc) : "v"(w), "v"(h));
}
// acc += w * {h.hi, h.hi}   (src1 broadcast-hi via op_sel)
__device__ __forceinline__ void pk_fma_H(v2f& acc, v2f w, v2f h) {
    asm("v_pk_fma_f32 %0, %1, %2, %0 op_sel:[0,1,0] op_sel_hi:[1,1,1]"
        : "+v"(acc) : "v"(w), "v"(h));
}
// out-of-place seeded variants (acc0 = bias)
__device__ __forceinline__ v2f pk_fma_L0(v2f w, v2f h, v2f c) {
    v2f d;
    asm("v_pk_fma_f32 %0, %1, %2, %3 op_sel:[0,0,0] op_sel_hi:[1,0,1]"
        : "=v"(d) : "v"(w), "v"(h), "v"(c));
    return d;
}

// DPP cross-lane mov (quad_perm, intra-quad).
template<int CTRL>
__device__ __forceinline__ float dppf(float v) {
    return __int_as_float(__builtin_amdgcn_mov_dpp(__float_as_int(v), CTRL, 0xF, 0xF, false));
}
#define QP_XOR1 0xB1   // quad_perm [1,0,3,2] : lane ^= 1
#define QP_XOR2 0x4E   // quad_perm [2,3,0,1] : lane ^= 2
#define QP_XOR3 0x1B   // quad_perm [3,2,1,0] : lane ^= 3

// 4 lanes per batch element; lane u = tid&3 owns hidden units {2u, 2u+1} as one
// v2f. h-state distributed as 4 pairs; allgather = 6 DPP movs (3 quad_perm x 2
// regs). Matmul consumes pairs via op_sel broadcast (no dup'd-h registers).
// XOR ordering: register slot m holds pair of element-units {2(u^m), 2(u^m)+1};
// weights gathered accordingly at load. Activations: exp2-based sigmoid/tanh
// with pre-scaled weights (CR=-log2e for r,z; CN=2log2e for n) and merged rcps.
__global__ __launch_bounds__(256, 4) void gru_seq2seq(
    const float* __restrict__ x,
    const float* __restrict__ eWih, const float* __restrict__ eWhh,
    const float* __restrict__ eBih, const float* __restrict__ eBhh,
    const float* __restrict__ dWih, const float* __restrict__ dWhh,
    const float* __restrict__ dBih, const float* __restrict__ dBhh,
    const float* __restrict__ fcW,  const float* __restrict__ fcB,
    float* __restrict__ out)
{
    const int tid = threadIdx.x;
    const int u   = tid & 3;                        // owns units 2u, 2u+1
    const int e0  = (int)blockIdx.x * 64 + (tid >> 2);

    const float CR = -1.44269504088896340736f;      // -log2(e)
    const float CN =  2.88539008177792681472f;      //  2*log2(e)

    const int r0 = 2*u, r1 = 2*u + 1;               // owned gate rows (per gate)

    // weights: index [2m+lh] multiplies h_{2(u^m)+lh} (XOR-of-pair order)
    v2f wr[8], wz[8], wn[8];
    v2f wirp, wizp, winp;                           // W_ih row pairs
    v2f brp, bzp, bnp, binp;                        // bias pairs

    auto load_w = [&](const float* Wih, const float* Whh,
                      const float* Bih, const float* Bhh) {
        #pragma unroll
        for (int m = 0; m < 4; ++m) {
            #pragma unroll
            for (int lh = 0; lh < 2; ++lh) {
                const int j = 2*(u^m) + lh;
                wr[2*m+lh] = v2f{ Whh[r0*8      + j] * CR, Whh[r1*8      + j] * CR };
                wz[2*m+lh] = v2f{ Whh[(r0+8)*8  + j] * CR, Whh[(r1+8)*8  + j] * CR };
                wn[2*m+lh] = v2f{ Whh[(r0+16)*8 + j] * CN, Whh[(r1+16)*8 + j] * CN };
            }
        }
        wirp = v2f{ Wih[r0]    * CR, Wih[r1]    * CR };
        wizp = v2f{ Wih[r0+8]  * CR, Wih[r1+8]  * CR };
        winp = v2f{ Wih[r0+16] * CN, Wih[r1+16] * CN };
        brp  = v2f{ (Bih[r0]   + Bhh[r0])   * CR, (Bih[r1]   + Bhh[r1])   * CR };
        bzp  = v2f{ (Bih[r0+8] + Bhh[r0+8]) * CR, (Bih[r1+8] + Bhh[r1+8]) * CR };
        bnp  = v2f{ Bhh[r0+16] * CN,              Bhh[r1+16] * CN };
        binp = v2f{ Bih[r0+16] * CN,              Bih[r1+16] * CN };
    };

    load_w(eWih, eWhh, eBih, eBhh);

    const v2f C_NEG2 = {-2.f, -2.f};
    const v2f C_ONE  = { 1.f,  1.f};
    const v2f C_HALF = { 0.5f, 0.5f};

    v2f hp[4];                                      // hp[m] = {h_{2(u^m)}, h_{2(u^m)+1}}
    #pragma unroll
    for (int m = 0; m < 4; ++m) hp[m] = v2f{0.f, 0.f};

    auto cell = [&](v2f xv) {                       // xv = {x, x}
        // gate matmuls: 24 pk_fma, h consumed via op_sel broadcast
        v2f ar = pk_fma_L0(wr[0], hp[0], brp);
        v2f az = pk_fma_L0(wz[0], hp[0], bzp);
        v2f an = pk_fma_L0(wn[0], hp[0], bnp);
        pk_fma_H(ar, wr[1], hp[0]);
        pk_fma_H(az, wz[1], hp[0]);
        pk_fma_H(an, wn[1], hp[0]);
        #pragma unroll
        for (int m = 1; m < 4; ++m) {
            pk_fma_L(ar, wr[2*m],   hp[m]);
            pk_fma_L(az, wz[2*m],   hp[m]);
            pk_fma_L(an, wn[2*m],   hp[m]);
            pk_fma_H(ar, wr[2*m+1], hp[m]);
            pk_fma_H(az, wz[2*m+1], hp[m]);
            pk_fma_H(an, wn[2*m+1], hp[m]);
        }
        const v2f sr = pk_fma(xv, wirp, ar);        // scaled pre-act r (rows 2u,2u+1)
        const v2f sz = pk_fma(xv, wizp, az);        // scaled pre-act z

        // 4 sigmoids, ONE rcp (merge across r/z and the row pair)
        const float er0 = exp2_fast(sr.x), er1 = exp2_fast(sr.y);
        const float ez0 = exp2_fast(sz.x), ez1 = exp2_fast(sz.y);
        const float dr0 = 1.0f + er0, dr1 = 1.0f + er1;
        const float dz0 = 1.0f + ez0, dz1 = 1.0f + ez1;
        const float P0  = dr0 * dz0,  P1  = dr1 * dz1;
        const float rp  = rcp_fast(P0 * P1);
        const float rpA = rp * P1,    rpB = rp * P0;    // 1/P0, 1/P1
        const v2f r01 = { dz0 * rpA, dz1 * rpB };
        const v2f z01 = { dr0 * rpA, dr1 * rpB };

        // n = tanh-form with shared rcp across the pair
        v2f pre = pk_fma(xv, winp, binp);
        pre = pk_fma(r01, an, pre);
        const float en0 = exp2_fast(pre.x), en1 = exp2_fast(pre.y);
        const float Dn0 = 1.0f + en0, Dn1 = 1.0f + en1;
        const float rpn = rcp_fast(Dn0 * Dn1);
        const v2f rn  = { rpn * Dn1, rpn * Dn0 };
        const v2f n01 = pk_fma(C_NEG2, rn, C_ONE);  // tanh

        const v2f hm = pk_fma(n01, C_NEG2 * C_HALF /* -1 */, hp[0]);  // h - n
        hp[0] = pk_fma(z01, hm, n01);               // h' = n + z*(h-n)

        // allgather: 6 DPP movs (intra-quad)
        const float g0 = hp[0].x, g1 = hp[0].y;
        hp[1] = v2f{ dppf<QP_XOR1>(g0), dppf<QP_XOR1>(g1) };
        hp[2] = v2f{ dppf<QP_XOR2>(g0), dppf<QP_XOR2>(g1) };
        hp[3] = v2f{ dppf<QP_XOR3>(g0), dppf<QP_XOR3>(g1) };
    };

    // ---------------- encoder: 512 steps, prefetch distance 2, tail peeled ----------------
    const float* xp = x + e0;
    float x0 = xp[0];
    float x1 = xp[BATCH];
    xp += 2 * (size_t)BATCH;
    #pragma unroll 2
    for (int t = 0; t < T_IN - 2; ++t) {
        const float x2 = *xp; xp += BATCH;
        cell(v2f{x0, x0});
        x0 = x1; x1 = x2;
    }
    cell(v2f{x0, x0});      // t = 510
    cell(v2f{x1, x1});      // t = 511; x1 == x[511] == decoder first input

    // ---------------- decoder: 128 steps ----------------
    load_w(dWih, dWhh, dBih, dBhh);
    const v2f fwp = v2f{ fcW[r0], fcW[r1] };
    const float fb = fcB[0];

    float inp = x1;
    float* outp = out + e0;
    #pragma unroll 1
    for (int t = 0; t < T_OUT; ++t) {
        cell(v2f{inp, inp});
        // y = fc(h'): pair-product then quad butterfly reduce
        const v2f ay = pk_mul(fwp, hp[0]);
        float s = ay.x + ay.y;
        s += dppf<QP_XOR1>(s);
        s += dppf<QP_XOR2>(s);
        const float y = s + fb;
        if (u == 0) outp[t * BATCH] = y;
        inp = y;
    }
}

extern "C" void kernel_launch(void* const* d_in, const int* in_sizes, int n_in,
                              void* d_out, int out_size, void* d_ws, size_t ws_size,
                              hipStream_t stream) {
    const float* x    = (const float*)d_in[0];
    const float* eWih = (const float*)d_in[1];
    const float* eWhh = (const float*)d_in[2];
    const float* eBih = (const float*)d_in[3];
    const float* eBhh = (const float*)d_in[4];
    const float* dWih = (const float*)d_in[5];
    const float* dWhh = (const float*)d_in[6];
    const float* dBih = (const float*)d_in[7];
    const float* dBhh = (const float*)d_in[8];
    const float* fcW  = (const float*)d_in[9];
    const float* fcB  = (const float*)d_in[10];
    float* out = (float*)d_out;

    dim3 grid(BATCH / 64);   // 1024 blocks; 4 lanes/elem, 64 elems/block
    dim3 block(256);
    gru_seq2seq<<<grid, block, 0, stream>>>(x, eWih, eWhh, eBih, eBhh,
                                            dWih, dWhh, dBih, dBhh,
                                            fcW, fcB, out);
}